// Round 4
// baseline (479.934 us; speedup 1.0000x reference)
//
#include <hip/hip_runtime.h>
#include <math.h>

// ---------------------------------------------------------------------------
// DifferentiablePooling: 2-layer GCN + softmax + spatial loss
// Round 4: gemm1 BM=64 (2x occupancy), LDS-staged coalesced f16 epilogue,
//          h stored f16, count fused into convert.
// ---------------------------------------------------------------------------

typedef __attribute__((ext_vector_type(8))) short bf16x8;
typedef __attribute__((ext_vector_type(4))) float f32x4;
typedef _Float16 f16;
typedef __attribute__((ext_vector_type(2))) _Float16 f16x2;
typedef __attribute__((ext_vector_type(4))) _Float16 f16x4;

__device__ inline unsigned short f32_to_bf16(float f) {
    unsigned u = __float_as_uint(f);
    unsigned r = u + 0x7FFFu + ((u >> 16) & 1u);   // RTNE; inputs are finite
    return (unsigned short)(r >> 16);
}
__device__ inline float bf16_to_f32(unsigned short h) {
    return __uint_as_float((unsigned)h << 16);
}

// ---- edge dtype detection (int64 vs int32 on device) ----------------------
__global__ void detect_i64_kernel(const unsigned* __restrict__ w, int* __restrict__ flag) {
    __shared__ int red[256];
    int cnt = 0;
    for (int i = threadIdx.x; i < 4096; i += 256)
        cnt += (w[2 * i + 1] == 0u) ? 1 : 0;   // high words of int64 are 0
    red[threadIdx.x] = cnt;
    __syncthreads();
    for (int s = 128; s > 0; s >>= 1) {
        if ((int)threadIdx.x < s) red[threadIdx.x] += red[threadIdx.x + s];
        __syncthreads();
    }
    if (threadIdx.x == 0) *flag = (red[0] > 2048) ? 1 : 0;
}

// convert + fused degree count (atomicAdd on dst)
__global__ void convert_edges_kernel(const void* __restrict__ ei, int* __restrict__ es,
                                     int* __restrict__ ed, int* __restrict__ cnt,
                                     int E, const int* __restrict__ flag) {
    int idx = blockIdx.x * blockDim.x + threadIdx.x;
    if (idx >= 2 * E) return;
    int v;
    if (*flag) v = (int)((const long long*)ei)[idx];
    else       v = ((const int*)ei)[idx];
    if (idx < E) es[idx] = v;
    else { ed[idx - E] = v; atomicAdd(&cnt[v], 1); }
}

// hierarchical scan: (1) per-block inclusive scan -> row_ptr[i+1], block totals
__global__ __launch_bounds__(1024) void scan_block_kernel(const int* __restrict__ cnt,
        int* __restrict__ row_ptr, int* __restrict__ btot, int n) {
    __shared__ int buf[1024];
    int i = blockIdx.x * 1024 + threadIdx.x;
    buf[threadIdx.x] = (i < n) ? cnt[i] : 0;
    __syncthreads();
    for (int off = 1; off < 1024; off <<= 1) {
        int t = ((int)threadIdx.x >= off) ? buf[threadIdx.x - off] : 0;
        __syncthreads();
        buf[threadIdx.x] += t;
        __syncthreads();
    }
    if (i < n) row_ptr[i + 1] = buf[threadIdx.x];
    if (threadIdx.x == 1023) btot[blockIdx.x] = buf[1023];
}

// (2) inclusive scan of block totals (nb <= 1024)
__global__ __launch_bounds__(1024) void scan_tops_kernel(int* __restrict__ btot, int nb) {
    __shared__ int buf[1024];
    buf[threadIdx.x] = ((int)threadIdx.x < nb) ? btot[threadIdx.x] : 0;
    __syncthreads();
    for (int off = 1; off < 1024; off <<= 1) {
        int t = ((int)threadIdx.x >= off) ? buf[threadIdx.x - off] : 0;
        __syncthreads();
        buf[threadIdx.x] += t;
        __syncthreads();
    }
    if ((int)threadIdx.x < nb) btot[threadIdx.x] = buf[threadIdx.x];
}

// (3) add block offsets; emit cursor + dinv
__global__ void scan_finalize_kernel(int* __restrict__ row_ptr, const int* __restrict__ btot,
        const int* __restrict__ cnt, int* __restrict__ cursor, float* __restrict__ dinv, int n) {
    int i = blockIdx.x * blockDim.x + threadIdx.x;
    if (i >= n) return;
    int blk = i >> 10;
    int off = blk ? btot[blk - 1] : 0;
    int incl = row_ptr[i + 1] + off;
    row_ptr[i + 1] = incl;
    cursor[i] = incl - cnt[i];
    dinv[i] = rsqrtf((float)(cnt[i] + 1));   // +1 self loop
    if (i == 0) row_ptr[0] = 0;
}

__global__ void scatter_kernel(const int* __restrict__ es, const int* __restrict__ ed,
                               int* __restrict__ cursor, int* __restrict__ csr_src, int E) {
    int e = blockIdx.x * blockDim.x + threadIdx.x;
    if (e < E) {
        int d = ed[e];
        int p = atomicAdd(&cursor[d], 1);
        csr_src[p] = es[e];
    }
}

// ---- W split+transpose: W[K][N] f32 -> Wt_hi/lo[N][K] bf16 ------------------
__global__ void wsplit_kernel(const float* __restrict__ W,
                              unsigned short* __restrict__ Wt_hi,
                              unsigned short* __restrict__ Wt_lo, int K, int N) {
    int idx = blockIdx.x * 256 + threadIdx.x;
    if (idx >= K * N) return;
    int k = idx / N, n = idx % N;
    float f = W[idx];
    unsigned short h = f32_to_bf16(f);
    unsigned short l = f32_to_bf16(f - bf16_to_f32(h));
    Wt_hi[(size_t)n * K + k] = h;
    Wt_lo[(size_t)n * K + k] = l;
}

// ---- GEMM1: h0[M,N](f16) = X[M,K] @ W[K,N] via MFMA bf16x3 ------------------
// 64x128 tile, 4 waves (2x2), each wave 32x64 = 2x4 frags of 16x16x32.
#define G1_BM 64
#define G1_BN 128
#define G1_BK 32
#define G1_LDK 40    // padded LDS row (bf16 elems): 80 B rows
#define G1_CLD 136   // epilogue f16 stage row (272 B, 16-B aligned)

__global__ __launch_bounds__(256) void gemm1_mfma(
        const float* __restrict__ X, const unsigned short* __restrict__ Wt_hi,
        const unsigned short* __restrict__ Wt_lo, f16* __restrict__ C,
        int M, int K, int N) {
    // manual carve: Ah[64*40] Al[64*40] Bh[128*40] Bl[128*40] = 15360 ushorts
    __shared__ __align__(16) unsigned short smem[15360];
    unsigned short* Ah = smem;            // 2560
    unsigned short* Al = smem + 2560;     // 2560
    unsigned short* Bh = smem + 5120;     // 5120
    unsigned short* Bl = smem + 10240;    // 5120

    const int tid  = threadIdx.x;
    const int lane = tid & 63;
    const int wave = tid >> 6;
    const int wm   = wave & 1;
    const int wn   = wave >> 1;
    const int m0   = blockIdx.x * G1_BM;
    const int n0   = blockIdx.y * G1_BN;

    const int arow_base = tid >> 3;   // + 32*i, i<2
    const int acq       = tid & 7;
    const int brow_base = tid >> 2;   // + 64*i, i<2
    const int bkq       = tid & 3;

    float4 aReg[2];
    uint4  bhReg[2], blReg[2];

    auto load_tile = [&](int k0) {
        #pragma unroll
        for (int i = 0; i < 2; ++i) {
            int r = arow_base + 32 * i;
            int gr = m0 + r;
            if (gr < M)
                aReg[i] = ((const float4*)X)[((size_t)gr * K + k0) / 4 + acq];
            else
                aReg[i] = make_float4(0.f, 0.f, 0.f, 0.f);
        }
        #pragma unroll
        for (int i = 0; i < 2; ++i) {
            int r = brow_base + 64 * i;
            size_t off = ((size_t)(n0 + r) * K + k0 + bkq * 8) / 8;
            bhReg[i] = ((const uint4*)Wt_hi)[off];
            blReg[i] = ((const uint4*)Wt_lo)[off];
        }
    };

    auto store_tile = [&]() {
        #pragma unroll
        for (int i = 0; i < 2; ++i) {
            int r = arow_base + 32 * i;
            float v[4] = {aReg[i].x, aReg[i].y, aReg[i].z, aReg[i].w};
            ushort4 hi, lo;
            unsigned short* hp = (unsigned short*)&hi;
            unsigned short* lp = (unsigned short*)&lo;
            #pragma unroll
            for (int j = 0; j < 4; ++j) {
                unsigned short h = f32_to_bf16(v[j]);
                hp[j] = h;
                lp[j] = f32_to_bf16(v[j] - bf16_to_f32(h));
            }
            *(ushort4*)&Ah[r * G1_LDK + acq * 4] = hi;
            *(ushort4*)&Al[r * G1_LDK + acq * 4] = lo;
        }
        #pragma unroll
        for (int i = 0; i < 2; ++i) {
            int r = brow_base + 64 * i;
            *(uint4*)&Bh[r * G1_LDK + bkq * 8] = bhReg[i];
            *(uint4*)&Bl[r * G1_LDK + bkq * 8] = blReg[i];
        }
    };

    f32x4 acc[2][4] = {};
    const int koff = (lane >> 4) * 8;
    const int frow = lane & 15;

    const int nk = K / G1_BK;
    load_tile(0);
    for (int t = 0; t < nk; ++t) {
        store_tile();
        __syncthreads();
        if (t + 1 < nk) load_tile((t + 1) * G1_BK);

        bf16x8 bhf[4], blf[4];
        #pragma unroll
        for (int nn = 0; nn < 4; ++nn) {
            int r = wn * 64 + nn * 16 + frow;
            bhf[nn] = *(const bf16x8*)&Bh[r * G1_LDK + koff];
            blf[nn] = *(const bf16x8*)&Bl[r * G1_LDK + koff];
        }
        #pragma unroll
        for (int mm = 0; mm < 2; ++mm) {
            int r = wm * 32 + mm * 16 + frow;
            bf16x8 ah = *(const bf16x8*)&Ah[r * G1_LDK + koff];
            bf16x8 al = *(const bf16x8*)&Al[r * G1_LDK + koff];
            #pragma unroll
            for (int nn = 0; nn < 4; ++nn)
                acc[mm][nn] = __builtin_amdgcn_mfma_f32_16x16x32_bf16(ah, bhf[nn], acc[mm][nn], 0, 0, 0);
            #pragma unroll
            for (int nn = 0; nn < 4; ++nn)
                acc[mm][nn] = __builtin_amdgcn_mfma_f32_16x16x32_bf16(ah, blf[nn], acc[mm][nn], 0, 0, 0);
            #pragma unroll
            for (int nn = 0; nn < 4; ++nn)
                acc[mm][nn] = __builtin_amdgcn_mfma_f32_16x16x32_bf16(al, bhf[nn], acc[mm][nn], 0, 0, 0);
        }
        __syncthreads();
    }

    // ---- coalesced epilogue: acc -> LDS (f16) -> 16B global stores ----------
    // C/D layout: col = lane&15, row = (lane>>4)*4 + i
    unsigned short* Ct = smem;   // [64][G1_CLD], reuse (all frag reads done)
    #pragma unroll
    for (int mm = 0; mm < 2; ++mm) {
        #pragma unroll
        for (int i = 0; i < 4; ++i) {
            int rt = wm * 32 + mm * 16 + (lane >> 4) * 4 + i;
            #pragma unroll
            for (int nn = 0; nn < 4; ++nn) {
                int ct = wn * 64 + nn * 16 + frow;
                f16 v = (f16)acc[mm][nn][i];
                Ct[rt * G1_CLD + ct] = *(unsigned short*)&v;
            }
        }
    }
    __syncthreads();
    #pragma unroll
    for (int i = 0; i < 4; ++i) {
        int idx = tid + 256 * i;          // 1024 chunks: 64 rows x 16 (16B each)
        int row = idx >> 4;
        int cq  = idx & 15;
        int gr = m0 + row;
        if (gr < M) {
            uint4 v = *(const uint4*)&Ct[row * G1_CLD + cq * 8];
            *(uint4*)(C + (size_t)gr * N + n0 + cq * 8) = v;
        }
    }
}

// ---- GEMM2: g[M,N](f16) = h[M,K](f16) @ W2[K,N](f32), f32 VALU --------------
template<int BM, int BN, int BK, int TM, int TN>
__global__ __launch_bounds__((BM / TM) * (BN / TN))
void gemm2_f32(const f16* __restrict__ A, const float* __restrict__ B, f16* __restrict__ C,
               int M, int K, int N) {
    constexpr int TX = BN / TN;
    constexpr int TY = BM / TM;
    constexpr int NTHREADS = TX * TY;
    __shared__ float As[BK][BM + 4];
    __shared__ float Bs[BK][BN + 4];
    const int tid = threadIdx.x;
    const int tx = tid % TX;
    const int ty = tid / TX;
    const int m0 = blockIdx.x * BM;
    const int n0 = blockIdx.y * BN;
    float acc[TM][TN] = {};
    for (int k0 = 0; k0 < K; k0 += BK) {
        // A staging: vectorized f16x4 (BM*BK/4 == NTHREADS slots)
        static_assert(BM * BK / 4 == NTHREADS, "A staging layout");
        {
            int r  = tid >> 2;          // row in tile
            int cq = tid & 3;           // 4-col group
            int gr = m0 + r;
            f16x4 v = (gr < M) ? *(const f16x4*)(A + (size_t)gr * K + k0 + cq * 4)
                               : (f16x4){0, 0, 0, 0};
            As[cq * 4 + 0][r] = (float)v.x;
            As[cq * 4 + 1][r] = (float)v.y;
            As[cq * 4 + 2][r] = (float)v.z;
            As[cq * 4 + 3][r] = (float)v.w;
        }
        #pragma unroll
        for (int idx = tid; idx < BK * BN; idx += NTHREADS) {
            int r = idx / BN, c = idx % BN;
            int gc = n0 + c;
            Bs[r][c] = (gc < N) ? B[(size_t)(k0 + r) * N + gc] : 0.f;
        }
        __syncthreads();
        #pragma unroll
        for (int k = 0; k < BK; ++k) {
            float a[TM], b[TN];
            #pragma unroll
            for (int i = 0; i < TM; ++i) a[i] = As[k][ty * TM + i];
            #pragma unroll
            for (int j = 0; j < TN; ++j) b[j] = Bs[k][tx * TN + j];
            #pragma unroll
            for (int i = 0; i < TM; ++i)
                #pragma unroll
                for (int j = 0; j < TN; ++j)
                    acc[i][j] = fmaf(a[i], b[j], acc[i][j]);
        }
        __syncthreads();
    }
    #pragma unroll
    for (int i = 0; i < TM; ++i) {
        int gr = m0 + ty * TM + i;
        if (gr >= M) continue;
        #pragma unroll
        for (int j = 0; j < TN; ++j) {
            int gc = n0 + tx * TN + j;
            if (gc < N) C[(size_t)gr * N + gc] = (f16)acc[i][j];
        }
    }
}

// ---- layer-1 aggregation: fp16 rows, wave per dst, unroll x2 ----------------
__device__ inline float4 ld_h4(const f16x4* __restrict__ p) {
    f16x4 v = *p;
    return make_float4((float)v.x, (float)v.y, (float)v.z, (float)v.w);
}

__global__ __launch_bounds__(256) void agg1_kernel(const f16* __restrict__ h0,
        const float* __restrict__ dinv, const int* __restrict__ row_ptr,
        const int* __restrict__ csr_src, const float* __restrict__ b1,
        f16* __restrict__ h, int n) {
    int wid = (int)((blockIdx.x * (size_t)blockDim.x + threadIdx.x) >> 6);
    int lane = threadIdx.x & 63;
    if (wid >= n) return;
    const f16x4* h0v = (const f16x4*)h0;    // row = 64 f16x4
    float di = dinv[wid];
    float4 v = ld_h4(&h0v[(size_t)wid * 64 + lane]);
    float self = di * di;
    float4 acc;
    acc.x = self * v.x; acc.y = self * v.y; acc.z = self * v.z; acc.w = self * v.w;
    int beg = row_ptr[wid], end = row_ptr[wid + 1];
    int j = beg;
    for (; j + 2 <= end; j += 2) {
        int s0 = csr_src[j], s1 = csr_src[j + 1];
        float n0 = dinv[s0] * di, n1 = dinv[s1] * di;
        float4 u0 = ld_h4(&h0v[(size_t)s0 * 64 + lane]);
        float4 u1 = ld_h4(&h0v[(size_t)s1 * 64 + lane]);
        acc.x = fmaf(n0, u0.x, acc.x); acc.y = fmaf(n0, u0.y, acc.y);
        acc.z = fmaf(n0, u0.z, acc.z); acc.w = fmaf(n0, u0.w, acc.w);
        acc.x = fmaf(n1, u1.x, acc.x); acc.y = fmaf(n1, u1.y, acc.y);
        acc.z = fmaf(n1, u1.z, acc.z); acc.w = fmaf(n1, u1.w, acc.w);
    }
    if (j < end) {
        int s0 = csr_src[j];
        float n0 = dinv[s0] * di;
        float4 u0 = ld_h4(&h0v[(size_t)s0 * 64 + lane]);
        acc.x = fmaf(n0, u0.x, acc.x); acc.y = fmaf(n0, u0.y, acc.y);
        acc.z = fmaf(n0, u0.z, acc.z); acc.w = fmaf(n0, u0.w, acc.w);
    }
    float4 bb = ((const float4*)b1)[lane];
    f16x4 out;
    out.x = (f16)fmaxf(acc.x + bb.x, 0.f);
    out.y = (f16)fmaxf(acc.y + bb.y, 0.f);
    out.z = (f16)fmaxf(acc.z + bb.z, 0.f);
    out.w = (f16)fmaxf(acc.w + bb.w, 0.f);
    ((f16x4*)h)[(size_t)wid * 64 + lane] = out;
}

// ---- layer-2 aggregation + bias + row softmax (f16 g, writes S + f16 shadow)
__global__ __launch_bounds__(256) void agg2_softmax_kernel(const f16* __restrict__ g,
        const float* __restrict__ dinv, const int* __restrict__ row_ptr,
        const int* __restrict__ csr_src, const float* __restrict__ b2,
        float* __restrict__ S, f16* __restrict__ Sh, int n, int KC) {
    int wid = (int)((blockIdx.x * (size_t)blockDim.x + threadIdx.x) >> 6);
    int lane = threadIdx.x & 63;
    if (wid >= n) return;
    bool act = lane < KC;
    float di = dinv[wid];
    float acc = 0.f;
    if (act) acc = di * di * (float)g[(size_t)wid * KC + lane];
    int beg = row_ptr[wid], end = row_ptr[wid + 1];
    for (int j = beg; j < end; ++j) {
        int s = csr_src[j];
        float nrm = dinv[s] * di;
        if (act) acc = fmaf(nrm, (float)g[(size_t)s * KC + lane], acc);
    }
    float val = act ? (acc + b2[lane]) : -INFINITY;
    float m = val;
    #pragma unroll
    for (int o = 32; o > 0; o >>= 1) m = fmaxf(m, __shfl_xor(m, o));
    float e = act ? expf(val - m) : 0.f;
    float ssum = e;
    #pragma unroll
    for (int o = 32; o > 0; o >>= 1) ssum += __shfl_xor(ssum, o);
    if (act) {
        float sv = e / ssum;
        S[(size_t)wid * KC + lane] = sv;
        Sh[(size_t)wid * KC + lane] = (f16)sv;
    }
}

// ---- spatial loss on f16 S-shadow: deterministic two-stage reduction -------
__global__ __launch_bounds__(256) void loss_partial_kernel(const int* __restrict__ es,
        const int* __restrict__ ed, const float* __restrict__ pos,
        const f16* __restrict__ Sh, float* __restrict__ parts, int E, int KC) {
    float local = 0.f;
    int stride = gridDim.x * blockDim.x;
    for (int e = blockIdx.x * blockDim.x + threadIdx.x; e < E; e += stride) {
        int s = es[e], d = ed[e];
        float2 ps = ((const float2*)pos)[s];
        float2 pd = ((const float2*)pos)[d];
        float dx = ps.x - pd.x, dy = ps.y - pd.y;
        float d2 = dx * dx + dy * dy;
        const f16x2* Sa = (const f16x2*)(Sh + (size_t)s * KC);
        const f16x2* Sb = (const f16x2*)(Sh + (size_t)d * KC);
        float dot = 0.f;
        #pragma unroll
        for (int k = 0; k < 25; ++k) {
            f16x2 a = Sa[k], b = Sb[k];
            dot = fmaf((float)a.x, (float)b.x, dot);
            dot = fmaf((float)a.y, (float)b.y, dot);
        }
        local = fmaf(d2, dot, local);
    }
    __shared__ float red[256];
    red[threadIdx.x] = local;
    __syncthreads();
    for (int s = 128; s > 0; s >>= 1) {
        if ((int)threadIdx.x < s) red[threadIdx.x] += red[threadIdx.x + s];
        __syncthreads();
    }
    if (threadIdx.x == 0) parts[blockIdx.x] = red[0];
}

__global__ __launch_bounds__(1024) void loss_final_kernel(const float* __restrict__ parts,
        const float* __restrict__ sw, float* __restrict__ out, float invE) {
    __shared__ float red[1024];
    red[threadIdx.x] = parts[threadIdx.x];
    __syncthreads();
    for (int s = 512; s > 0; s >>= 1) {
        if ((int)threadIdx.x < s) red[threadIdx.x] += red[threadIdx.x + s];
        __syncthreads();
    }
    if (threadIdx.x == 0) out[0] = sw[0] * red[0] * invE;
}

// ---------------------------------------------------------------------------
extern "C" void kernel_launch(void* const* d_in, const int* in_sizes, int n_in,
                              void* d_out, int out_size, void* d_ws, size_t ws_size,
                              hipStream_t stream) {
    const float* x   = (const float*)d_in[0];
    const float* pos = (const float*)d_in[1];
    const float* W1  = (const float*)d_in[2];
    const float* b1  = (const float*)d_in[3];
    const float* W2  = (const float*)d_in[4];
    const float* b2  = (const float*)d_in[5];
    const float* sw  = (const float*)d_in[6];
    const void*  ei  = d_in[7];

    const int DH  = in_sizes[3];           // 256
    const int KC  = in_sizes[5];           // 50
    const int DIN = in_sizes[2] / DH;      // 512
    const int n   = in_sizes[0] / DIN;     // 50000
    const int E   = in_sizes[7] / 2;       // 800000

    char* p = (char*)d_ws;
    auto alloc = [&](size_t bytes) {
        char* r = p;
        p += (bytes + 255) & ~(size_t)255;
        return r;
    };
    int*   flag    = (int*)alloc(256);
    int*   es      = (int*)alloc((size_t)E * 4);
    int*   ed      = (int*)alloc((size_t)E * 4);
    int*   cnt     = (int*)alloc((size_t)n * 4);
    int*   cursor  = (int*)alloc((size_t)n * 4);
    int*   row_ptr = (int*)alloc(((size_t)n + 1) * 4);
    int*   btot    = (int*)alloc(1024 * 4);
    int*   csr     = (int*)alloc((size_t)E * 4);
    float* dinv    = (float*)alloc((size_t)n * 4);
    float* parts   = (float*)alloc(1024 * 4);
    unsigned short* Wt_hi = (unsigned short*)alloc((size_t)DIN * DH * 2);
    unsigned short* Wt_lo = (unsigned short*)alloc((size_t)DIN * DH * 2);
    f16*   h0      = (f16*)alloc((size_t)n * DH * 2);
    f16*   h       = (f16*)alloc((size_t)n * DH * 2);
    f16*   g       = (f16*)alloc((size_t)n * KC * 2);
    f16*   Sh      = (f16*)alloc((size_t)n * KC * 2);

    float* S    = (float*)d_out;
    float* Lout = S + (size_t)n * KC;

    const int nb = (n + 1023) / 1024;

    hipMemsetAsync(cnt, 0, (size_t)n * 4, stream);
    detect_i64_kernel<<<1, 256, 0, stream>>>((const unsigned*)ei, flag);
    convert_edges_kernel<<<(2 * E + 255) / 256, 256, 0, stream>>>(ei, es, ed, cnt, E, flag);
    scan_block_kernel<<<nb, 1024, 0, stream>>>(cnt, row_ptr, btot, n);
    scan_tops_kernel<<<1, 1024, 0, stream>>>(btot, nb);
    scan_finalize_kernel<<<(n + 255) / 256, 256, 0, stream>>>(row_ptr, btot, cnt, cursor, dinv, n);
    scatter_kernel<<<(E + 255) / 256, 256, 0, stream>>>(es, ed, cursor, csr, E);

    // W1 split/transpose for MFMA GEMM1
    wsplit_kernel<<<(DIN * DH + 255) / 256, 256, 0, stream>>>(W1, Wt_hi, Wt_lo, DIN, DH);

    // h0 = x @ W1   (MFMA bf16x3, fp16 output)
    dim3 g1((n + G1_BM - 1) / G1_BM, DH / G1_BN);
    gemm1_mfma<<<g1, 256, 0, stream>>>(x, Wt_hi, Wt_lo, h0, n, DIN, DH);

    // h = relu(Ahat @ h0 + b1)  (f16 out)
    agg1_kernel<<<(int)(((size_t)n * 64 + 255) / 256), 256, 0, stream>>>(
        h0, dinv, row_ptr, csr, b1, h, n);

    // g = h @ W2  (f16 in/out)
    dim3 g2((n + 63) / 64, (KC + 63) / 64);
    gemm2_f32<64, 64, 16, 4, 4><<<g2, 256, 0, stream>>>(h, W2, g, n, DH, KC);

    // s = Ahat @ g + b2 ; S = softmax(s)  (+ fp16 shadow for loss)
    agg2_softmax_kernel<<<(int)(((size_t)n * 64 + 255) / 256), 256, 0, stream>>>(
        g, dinv, row_ptr, csr, b2, S, Sh, n, KC);

    // L = sw * sum(d2 * <S_s, S_d>) / E
    loss_partial_kernel<<<1024, 256, 0, stream>>>(es, ed, pos, Sh, parts, E, KC);
    loss_final_kernel<<<1, 1024, 0, stream>>>(parts, sw, Lout, 1.0f / (float)E);
}

// Round 5
// 425.767 us; speedup vs baseline: 1.1272x; 1.1272x over previous
//
#include <hip/hip_runtime.h>
#include <math.h>

// ---------------------------------------------------------------------------
// DifferentiablePooling: 2-layer GCN + softmax + spatial loss
// Round 5: gemm1 back to BM=128; B fragments read direct from global (L2),
//          A-only LDS (20.5 KB). Keep h f16, vectorized gemm2, fused count.
// ---------------------------------------------------------------------------

typedef __attribute__((ext_vector_type(8))) short bf16x8;
typedef __attribute__((ext_vector_type(4))) float f32x4;
typedef _Float16 f16;
typedef __attribute__((ext_vector_type(2))) _Float16 f16x2;
typedef __attribute__((ext_vector_type(4))) _Float16 f16x4;

__device__ inline unsigned short f32_to_bf16(float f) {
    unsigned u = __float_as_uint(f);
    unsigned r = u + 0x7FFFu + ((u >> 16) & 1u);   // RTNE; inputs are finite
    return (unsigned short)(r >> 16);
}
__device__ inline float bf16_to_f32(unsigned short h) {
    return __uint_as_float((unsigned)h << 16);
}

// ---- edge dtype detection (int64 vs int32 on device) ----------------------
__global__ void detect_i64_kernel(const unsigned* __restrict__ w, int* __restrict__ flag) {
    __shared__ int red[256];
    int cnt = 0;
    for (int i = threadIdx.x; i < 4096; i += 256)
        cnt += (w[2 * i + 1] == 0u) ? 1 : 0;   // high words of int64 are 0
    red[threadIdx.x] = cnt;
    __syncthreads();
    for (int s = 128; s > 0; s >>= 1) {
        if ((int)threadIdx.x < s) red[threadIdx.x] += red[threadIdx.x + s];
        __syncthreads();
    }
    if (threadIdx.x == 0) *flag = (red[0] > 2048) ? 1 : 0;
}

// convert + fused degree count (atomicAdd on dst)
__global__ void convert_edges_kernel(const void* __restrict__ ei, int* __restrict__ es,
                                     int* __restrict__ ed, int* __restrict__ cnt,
                                     int E, const int* __restrict__ flag) {
    int idx = blockIdx.x * blockDim.x + threadIdx.x;
    if (idx >= 2 * E) return;
    int v;
    if (*flag) v = (int)((const long long*)ei)[idx];
    else       v = ((const int*)ei)[idx];
    if (idx < E) es[idx] = v;
    else { ed[idx - E] = v; atomicAdd(&cnt[v], 1); }
}

// hierarchical scan: (1) per-block inclusive scan -> row_ptr[i+1], block totals
__global__ __launch_bounds__(1024) void scan_block_kernel(const int* __restrict__ cnt,
        int* __restrict__ row_ptr, int* __restrict__ btot, int n) {
    __shared__ int buf[1024];
    int i = blockIdx.x * 1024 + threadIdx.x;
    buf[threadIdx.x] = (i < n) ? cnt[i] : 0;
    __syncthreads();
    for (int off = 1; off < 1024; off <<= 1) {
        int t = ((int)threadIdx.x >= off) ? buf[threadIdx.x - off] : 0;
        __syncthreads();
        buf[threadIdx.x] += t;
        __syncthreads();
    }
    if (i < n) row_ptr[i + 1] = buf[threadIdx.x];
    if (threadIdx.x == 1023) btot[blockIdx.x] = buf[1023];
}

// (2) inclusive scan of block totals (nb <= 1024)
__global__ __launch_bounds__(1024) void scan_tops_kernel(int* __restrict__ btot, int nb) {
    __shared__ int buf[1024];
    buf[threadIdx.x] = ((int)threadIdx.x < nb) ? btot[threadIdx.x] : 0;
    __syncthreads();
    for (int off = 1; off < 1024; off <<= 1) {
        int t = ((int)threadIdx.x >= off) ? buf[threadIdx.x - off] : 0;
        __syncthreads();
        buf[threadIdx.x] += t;
        __syncthreads();
    }
    if ((int)threadIdx.x < nb) btot[threadIdx.x] = buf[threadIdx.x];
}

// (3) add block offsets; emit cursor + dinv
__global__ void scan_finalize_kernel(int* __restrict__ row_ptr, const int* __restrict__ btot,
        const int* __restrict__ cnt, int* __restrict__ cursor, float* __restrict__ dinv, int n) {
    int i = blockIdx.x * blockDim.x + threadIdx.x;
    if (i >= n) return;
    int blk = i >> 10;
    int off = blk ? btot[blk - 1] : 0;
    int incl = row_ptr[i + 1] + off;
    row_ptr[i + 1] = incl;
    cursor[i] = incl - cnt[i];
    dinv[i] = rsqrtf((float)(cnt[i] + 1));   // +1 self loop
    if (i == 0) row_ptr[0] = 0;
}

__global__ void scatter_kernel(const int* __restrict__ es, const int* __restrict__ ed,
                               int* __restrict__ cursor, int* __restrict__ csr_src, int E) {
    int e = blockIdx.x * blockDim.x + threadIdx.x;
    if (e < E) {
        int d = ed[e];
        int p = atomicAdd(&cursor[d], 1);
        csr_src[p] = es[e];
    }
}

// ---- W split+transpose: W[K][N] f32 -> Wt_hi/lo[N][K] bf16 ------------------
__global__ void wsplit_kernel(const float* __restrict__ W,
                              unsigned short* __restrict__ Wt_hi,
                              unsigned short* __restrict__ Wt_lo, int K, int N) {
    int idx = blockIdx.x * 256 + threadIdx.x;
    if (idx >= K * N) return;
    int k = idx / N, n = idx % N;
    float f = W[idx];
    unsigned short h = f32_to_bf16(f);
    unsigned short l = f32_to_bf16(f - bf16_to_f32(h));
    Wt_hi[(size_t)n * K + k] = h;
    Wt_lo[(size_t)n * K + k] = l;
}

// ---- GEMM1: h0[M,N](f16) = X[M,K] @ W[K,N] via MFMA bf16x3 ------------------
// 128x128 tile, 4 waves (2x2), each wave 64x64 = 4x4 frags of 16x16x32.
// A staged in LDS (hi/lo); B fragments read DIRECT from global (L2-resident).
#define G1_BM 128
#define G1_BN 128
#define G1_BK 32
#define G1_LDK 40   // padded LDS row (bf16 elems): 80 B rows -> conflict-free frags

__global__ __launch_bounds__(256) void gemm1_mfma(
        const float* __restrict__ X, const unsigned short* __restrict__ Wt_hi,
        const unsigned short* __restrict__ Wt_lo, f16* __restrict__ C,
        int M, int K, int N) {
    __shared__ __align__(16) unsigned short Ah[G1_BM * G1_LDK];   // 10240 B
    __shared__ __align__(16) unsigned short Al[G1_BM * G1_LDK];   // 10240 B

    const int tid  = threadIdx.x;
    const int lane = tid & 63;
    const int wave = tid >> 6;
    const int wm   = wave & 1;
    const int wn   = wave >> 1;
    const int m0   = blockIdx.x * G1_BM;
    const int n0   = blockIdx.y * G1_BN;

    const int arow_base = tid >> 3;   // + 32*i, i<4
    const int acq       = tid & 7;

    float4 aReg[4];

    auto load_tile = [&](int k0) {
        #pragma unroll
        for (int i = 0; i < 4; ++i) {
            int r = arow_base + 32 * i;
            int gr = m0 + r;
            if (gr < M)
                aReg[i] = ((const float4*)X)[((size_t)gr * K + k0) / 4 + acq];
            else
                aReg[i] = make_float4(0.f, 0.f, 0.f, 0.f);
        }
    };

    auto store_tile = [&]() {
        #pragma unroll
        for (int i = 0; i < 4; ++i) {
            int r = arow_base + 32 * i;
            float v[4] = {aReg[i].x, aReg[i].y, aReg[i].z, aReg[i].w};
            ushort4 hi, lo;
            unsigned short* hp = (unsigned short*)&hi;
            unsigned short* lp = (unsigned short*)&lo;
            #pragma unroll
            for (int j = 0; j < 4; ++j) {
                unsigned short h = f32_to_bf16(v[j]);
                hp[j] = h;
                lp[j] = f32_to_bf16(v[j] - bf16_to_f32(h));
            }
            *(ushort4*)&Ah[r * G1_LDK + acq * 4] = hi;
            *(ushort4*)&Al[r * G1_LDK + acq * 4] = lo;
        }
    };

    f32x4 acc[4][4] = {};
    const int koff = (lane >> 4) * 8;
    const int frow = lane & 15;

    // per-lane B row bases (row = output column), stride K bf16
    const unsigned short* Bh_base = Wt_hi + (size_t)(n0 + wn * 64 + frow) * K + koff;
    const unsigned short* Bl_base = Wt_lo + (size_t)(n0 + wn * 64 + frow) * K + koff;

    const int nk = K / G1_BK;
    load_tile(0);
    for (int t = 0; t < nk; ++t) {
        store_tile();
        __syncthreads();
        if (t + 1 < nk) load_tile((t + 1) * G1_BK);

        const int kk = t * G1_BK;
        bf16x8 bhf[4], blf[4];
        #pragma unroll
        for (int nn = 0; nn < 4; ++nn) {
            bhf[nn] = *(const bf16x8*)(Bh_base + (size_t)nn * 16 * K + kk);
            blf[nn] = *(const bf16x8*)(Bl_base + (size_t)nn * 16 * K + kk);
        }
        #pragma unroll
        for (int mm = 0; mm < 4; ++mm) {
            int r = wm * 64 + mm * 16 + frow;
            bf16x8 ah = *(const bf16x8*)&Ah[r * G1_LDK + koff];
            bf16x8 al = *(const bf16x8*)&Al[r * G1_LDK + koff];
            #pragma unroll
            for (int nn = 0; nn < 4; ++nn)
                acc[mm][nn] = __builtin_amdgcn_mfma_f32_16x16x32_bf16(ah, bhf[nn], acc[mm][nn], 0, 0, 0);
            #pragma unroll
            for (int nn = 0; nn < 4; ++nn)
                acc[mm][nn] = __builtin_amdgcn_mfma_f32_16x16x32_bf16(ah, blf[nn], acc[mm][nn], 0, 0, 0);
            #pragma unroll
            for (int nn = 0; nn < 4; ++nn)
                acc[mm][nn] = __builtin_amdgcn_mfma_f32_16x16x32_bf16(al, bhf[nn], acc[mm][nn], 0, 0, 0);
        }
        __syncthreads();
    }

    // C/D layout: col = lane&15, row = (lane>>4)*4 + i
    #pragma unroll
    for (int mm = 0; mm < 4; ++mm) {
        #pragma unroll
        for (int i = 0; i < 4; ++i) {
            int gr = m0 + wm * 64 + mm * 16 + (lane >> 4) * 4 + i;
            if (gr >= M) continue;
            #pragma unroll
            for (int nn = 0; nn < 4; ++nn) {
                int gc = n0 + wn * 64 + nn * 16 + frow;
                C[(size_t)gr * N + gc] = (f16)acc[mm][nn][i];
            }
        }
    }
}

// ---- GEMM2: g[M,N](f16) = h[M,K](f16) @ W2[K,N](f32), f32 VALU --------------
template<int BM, int BN, int BK, int TM, int TN>
__global__ __launch_bounds__((BM / TM) * (BN / TN))
void gemm2_f32(const f16* __restrict__ A, const float* __restrict__ B, f16* __restrict__ C,
               int M, int K, int N) {
    constexpr int TX = BN / TN;
    constexpr int TY = BM / TM;
    constexpr int NTHREADS = TX * TY;
    __shared__ float As[BK][BM + 4];
    __shared__ float Bs[BK][BN + 4];
    const int tid = threadIdx.x;
    const int tx = tid % TX;
    const int ty = tid / TX;
    const int m0 = blockIdx.x * BM;
    const int n0 = blockIdx.y * BN;
    float acc[TM][TN] = {};
    for (int k0 = 0; k0 < K; k0 += BK) {
        // A staging: vectorized f16x4 (BM*BK/4 == NTHREADS slots)
        static_assert(BM * BK / 4 == NTHREADS, "A staging layout");
        {
            int r  = tid >> 2;          // row in tile
            int cq = tid & 3;           // 4-col group
            int gr = m0 + r;
            f16x4 v = (gr < M) ? *(const f16x4*)(A + (size_t)gr * K + k0 + cq * 4)
                               : (f16x4){0, 0, 0, 0};
            As[cq * 4 + 0][r] = (float)v.x;
            As[cq * 4 + 1][r] = (float)v.y;
            As[cq * 4 + 2][r] = (float)v.z;
            As[cq * 4 + 3][r] = (float)v.w;
        }
        #pragma unroll
        for (int idx = tid; idx < BK * BN; idx += NTHREADS) {
            int r = idx / BN, c = idx % BN;
            int gc = n0 + c;
            Bs[r][c] = (gc < N) ? B[(size_t)(k0 + r) * N + gc] : 0.f;
        }
        __syncthreads();
        #pragma unroll
        for (int k = 0; k < BK; ++k) {
            float a[TM], b[TN];
            #pragma unroll
            for (int i = 0; i < TM; ++i) a[i] = As[k][ty * TM + i];
            #pragma unroll
            for (int j = 0; j < TN; ++j) b[j] = Bs[k][tx * TN + j];
            #pragma unroll
            for (int i = 0; i < TM; ++i)
                #pragma unroll
                for (int j = 0; j < TN; ++j)
                    acc[i][j] = fmaf(a[i], b[j], acc[i][j]);
        }
        __syncthreads();
    }
    #pragma unroll
    for (int i = 0; i < TM; ++i) {
        int gr = m0 + ty * TM + i;
        if (gr >= M) continue;
        #pragma unroll
        for (int j = 0; j < TN; ++j) {
            int gc = n0 + tx * TN + j;
            if (gc < N) C[(size_t)gr * N + gc] = (f16)acc[i][j];
        }
    }
}

// ---- layer-1 aggregation: fp16 rows, wave per dst, unroll x2 ----------------
__device__ inline float4 ld_h4(const f16x4* __restrict__ p) {
    f16x4 v = *p;
    return make_float4((float)v.x, (float)v.y, (float)v.z, (float)v.w);
}

__global__ __launch_bounds__(256) void agg1_kernel(const f16* __restrict__ h0,
        const float* __restrict__ dinv, const int* __restrict__ row_ptr,
        const int* __restrict__ csr_src, const float* __restrict__ b1,
        f16* __restrict__ h, int n) {
    int wid = (int)((blockIdx.x * (size_t)blockDim.x + threadIdx.x) >> 6);
    int lane = threadIdx.x & 63;
    if (wid >= n) return;
    const f16x4* h0v = (const f16x4*)h0;    // row = 64 f16x4
    float di = dinv[wid];
    float4 v = ld_h4(&h0v[(size_t)wid * 64 + lane]);
    float self = di * di;
    float4 acc;
    acc.x = self * v.x; acc.y = self * v.y; acc.z = self * v.z; acc.w = self * v.w;
    int beg = row_ptr[wid], end = row_ptr[wid + 1];
    int j = beg;
    for (; j + 2 <= end; j += 2) {
        int s0 = csr_src[j], s1 = csr_src[j + 1];
        float n0 = dinv[s0] * di, n1 = dinv[s1] * di;
        float4 u0 = ld_h4(&h0v[(size_t)s0 * 64 + lane]);
        float4 u1 = ld_h4(&h0v[(size_t)s1 * 64 + lane]);
        acc.x = fmaf(n0, u0.x, acc.x); acc.y = fmaf(n0, u0.y, acc.y);
        acc.z = fmaf(n0, u0.z, acc.z); acc.w = fmaf(n0, u0.w, acc.w);
        acc.x = fmaf(n1, u1.x, acc.x); acc.y = fmaf(n1, u1.y, acc.y);
        acc.z = fmaf(n1, u1.z, acc.z); acc.w = fmaf(n1, u1.w, acc.w);
    }
    if (j < end) {
        int s0 = csr_src[j];
        float n0 = dinv[s0] * di;
        float4 u0 = ld_h4(&h0v[(size_t)s0 * 64 + lane]);
        acc.x = fmaf(n0, u0.x, acc.x); acc.y = fmaf(n0, u0.y, acc.y);
        acc.z = fmaf(n0, u0.z, acc.z); acc.w = fmaf(n0, u0.w, acc.w);
    }
    float4 bb = ((const float4*)b1)[lane];
    f16x4 out;
    out.x = (f16)fmaxf(acc.x + bb.x, 0.f);
    out.y = (f16)fmaxf(acc.y + bb.y, 0.f);
    out.z = (f16)fmaxf(acc.z + bb.z, 0.f);
    out.w = (f16)fmaxf(acc.w + bb.w, 0.f);
    ((f16x4*)h)[(size_t)wid * 64 + lane] = out;
}

// ---- layer-2 aggregation + bias + row softmax (f16 g, writes S + f16 shadow)
__global__ __launch_bounds__(256) void agg2_softmax_kernel(const f16* __restrict__ g,
        const float* __restrict__ dinv, const int* __restrict__ row_ptr,
        const int* __restrict__ csr_src, const float* __restrict__ b2,
        float* __restrict__ S, f16* __restrict__ Sh, int n, int KC) {
    int wid = (int)((blockIdx.x * (size_t)blockDim.x + threadIdx.x) >> 6);
    int lane = threadIdx.x & 63;
    if (wid >= n) return;
    bool act = lane < KC;
    float di = dinv[wid];
    float acc = 0.f;
    if (act) acc = di * di * (float)g[(size_t)wid * KC + lane];
    int beg = row_ptr[wid], end = row_ptr[wid + 1];
    for (int j = beg; j < end; ++j) {
        int s = csr_src[j];
        float nrm = dinv[s] * di;
        if (act) acc = fmaf(nrm, (float)g[(size_t)s * KC + lane], acc);
    }
    float val = act ? (acc + b2[lane]) : -INFINITY;
    float m = val;
    #pragma unroll
    for (int o = 32; o > 0; o >>= 1) m = fmaxf(m, __shfl_xor(m, o));
    float e = act ? expf(val - m) : 0.f;
    float ssum = e;
    #pragma unroll
    for (int o = 32; o > 0; o >>= 1) ssum += __shfl_xor(ssum, o);
    if (act) {
        float sv = e / ssum;
        S[(size_t)wid * KC + lane] = sv;
        Sh[(size_t)wid * KC + lane] = (f16)sv;
    }
}

// ---- spatial loss on f16 S-shadow: deterministic two-stage reduction -------
__global__ __launch_bounds__(256) void loss_partial_kernel(const int* __restrict__ es,
        const int* __restrict__ ed, const float* __restrict__ pos,
        const f16* __restrict__ Sh, float* __restrict__ parts, int E, int KC) {
    float local = 0.f;
    int stride = gridDim.x * blockDim.x;
    for (int e = blockIdx.x * blockDim.x + threadIdx.x; e < E; e += stride) {
        int s = es[e], d = ed[e];
        float2 ps = ((const float2*)pos)[s];
        float2 pd = ((const float2*)pos)[d];
        float dx = ps.x - pd.x, dy = ps.y - pd.y;
        float d2 = dx * dx + dy * dy;
        const f16x2* Sa = (const f16x2*)(Sh + (size_t)s * KC);
        const f16x2* Sb = (const f16x2*)(Sh + (size_t)d * KC);
        float dot = 0.f;
        #pragma unroll
        for (int k = 0; k < 25; ++k) {
            f16x2 a = Sa[k], b = Sb[k];
            dot = fmaf((float)a.x, (float)b.x, dot);
            dot = fmaf((float)a.y, (float)b.y, dot);
        }
        local = fmaf(d2, dot, local);
    }
    __shared__ float red[256];
    red[threadIdx.x] = local;
    __syncthreads();
    for (int s = 128; s > 0; s >>= 1) {
        if ((int)threadIdx.x < s) red[threadIdx.x] += red[threadIdx.x + s];
        __syncthreads();
    }
    if (threadIdx.x == 0) parts[blockIdx.x] = red[0];
}

__global__ __launch_bounds__(1024) void loss_final_kernel(const float* __restrict__ parts,
        const float* __restrict__ sw, float* __restrict__ out, float invE) {
    __shared__ float red[1024];
    red[threadIdx.x] = parts[threadIdx.x];
    __syncthreads();
    for (int s = 512; s > 0; s >>= 1) {
        if ((int)threadIdx.x < s) red[threadIdx.x] += red[threadIdx.x + s];
        __syncthreads();
    }
    if (threadIdx.x == 0) out[0] = sw[0] * red[0] * invE;
}

// ---------------------------------------------------------------------------
extern "C" void kernel_launch(void* const* d_in, const int* in_sizes, int n_in,
                              void* d_out, int out_size, void* d_ws, size_t ws_size,
                              hipStream_t stream) {
    const float* x   = (const float*)d_in[0];
    const float* pos = (const float*)d_in[1];
    const float* W1  = (const float*)d_in[2];
    const float* b1  = (const float*)d_in[3];
    const float* W2  = (const float*)d_in[4];
    const float* b2  = (const float*)d_in[5];
    const float* sw  = (const float*)d_in[6];
    const void*  ei  = d_in[7];

    const int DH  = in_sizes[3];           // 256
    const int KC  = in_sizes[5];           // 50
    const int DIN = in_sizes[2] / DH;      // 512
    const int n   = in_sizes[0] / DIN;     // 50000
    const int E   = in_sizes[7] / 2;       // 800000

    char* p = (char*)d_ws;
    auto alloc = [&](size_t bytes) {
        char* r = p;
        p += (bytes + 255) & ~(size_t)255;
        return r;
    };
    int*   flag    = (int*)alloc(256);
    int*   es      = (int*)alloc((size_t)E * 4);
    int*   ed      = (int*)alloc((size_t)E * 4);
    int*   cnt     = (int*)alloc((size_t)n * 4);
    int*   cursor  = (int*)alloc((size_t)n * 4);
    int*   row_ptr = (int*)alloc(((size_t)n + 1) * 4);
    int*   btot    = (int*)alloc(1024 * 4);
    int*   csr     = (int*)alloc((size_t)E * 4);
    float* dinv    = (float*)alloc((size_t)n * 4);
    float* parts   = (float*)alloc(1024 * 4);
    unsigned short* Wt_hi = (unsigned short*)alloc((size_t)DIN * DH * 2);
    unsigned short* Wt_lo = (unsigned short*)alloc((size_t)DIN * DH * 2);
    f16*   h0      = (f16*)alloc((size_t)n * DH * 2);
    f16*   h       = (f16*)alloc((size_t)n * DH * 2);
    f16*   g       = (f16*)alloc((size_t)n * KC * 2);
    f16*   Sh      = (f16*)alloc((size_t)n * KC * 2);

    float* S    = (float*)d_out;
    float* Lout = S + (size_t)n * KC;

    const int nb = (n + 1023) / 1024;

    hipMemsetAsync(cnt, 0, (size_t)n * 4, stream);
    detect_i64_kernel<<<1, 256, 0, stream>>>((const unsigned*)ei, flag);
    convert_edges_kernel<<<(2 * E + 255) / 256, 256, 0, stream>>>(ei, es, ed, cnt, E, flag);
    scan_block_kernel<<<nb, 1024, 0, stream>>>(cnt, row_ptr, btot, n);
    scan_tops_kernel<<<1, 1024, 0, stream>>>(btot, nb);
    scan_finalize_kernel<<<(n + 255) / 256, 256, 0, stream>>>(row_ptr, btot, cnt, cursor, dinv, n);
    scatter_kernel<<<(E + 255) / 256, 256, 0, stream>>>(es, ed, cursor, csr, E);

    // W1 split/transpose for MFMA GEMM1
    wsplit_kernel<<<(DIN * DH + 255) / 256, 256, 0, stream>>>(W1, Wt_hi, Wt_lo, DIN, DH);

    // h0 = x @ W1   (MFMA bf16x3, fp16 output; B direct from L2)
    dim3 g1((n + G1_BM - 1) / G1_BM, DH / G1_BN);
    gemm1_mfma<<<g1, 256, 0, stream>>>(x, Wt_hi, Wt_lo, h0, n, DIN, DH);

    // h = relu(Ahat @ h0 + b1)  (f16 out)
    agg1_kernel<<<(int)(((size_t)n * 64 + 255) / 256), 256, 0, stream>>>(
        h0, dinv, row_ptr, csr, b1, h, n);

    // g = h @ W2  (f16 in/out)
    dim3 g2((n + 63) / 64, (KC + 63) / 64);
    gemm2_f32<64, 64, 16, 4, 4><<<g2, 256, 0, stream>>>(h, W2, g, n, DH, KC);

    // s = Ahat @ g + b2 ; S = softmax(s)  (+ fp16 shadow for loss)
    agg2_softmax_kernel<<<(int)(((size_t)n * 64 + 255) / 256), 256, 0, stream>>>(
        g, dinv, row_ptr, csr, b2, S, Sh, n, KC);

    // L = sw * sum(d2 * <S_s, S_d>) / E
    loss_partial_kernel<<<1024, 256, 0, stream>>>(es, ed, pos, Sh, parts, E, KC);
    loss_final_kernel<<<1, 1024, 0, stream>>>(parts, sw, Lout, 1.0f / (float)E);
}